// Round 1
// baseline (2349.655 us; speedup 1.0000x reference)
//
#include <hip/hip_runtime.h>
#include <math.h>

#define NWAY 5
#define KSHOT 5
#define BB 4
#define QQ 75
#define CC 640
#define MM 196
#define CK 32

// ws layout (units: 4-byte elements)
#define SUP_OFF   0
#define SUP_SZ    (BB*NWAY*CC*MM)          // 2,508,800
#define INVQ_OFF  (SUP_OFF + SUP_SZ)
#define INVQ_SZ   (BB*QQ*MM)               // 58,800
#define CMAX_OFF  (INVQ_OFF + INVQ_SZ)
#define CMAX_SZ   (BB*QQ*NWAY*MM)          // 294,000
#define CARG_OFF  (CMAX_OFF + CMAX_SZ)
#define CARG_SZ   (BB*QQ*NWAY*MM)
#define SLOSS_OFF (CARG_OFF + CARG_SZ)     // +300 -> total ~12.6 MB

// ---------------- kernel 1: support k-shot mean + column L2-normalize ----------------
__global__ void k_prep_support(const float* __restrict__ sx, float* __restrict__ ws) {
    int blk = blockIdx.x;            // b*NWAY + n
    int b = blk / NWAY, n = blk % NWAY;
    float* sup = ws + SUP_OFF + (size_t)blk * CC * MM;
    const float* base = sx + ((size_t)(b * (NWAY*KSHOT) + n * KSHOT)) * CC * MM;
    int t = threadIdx.x;
    for (int idx = t; idx < CC * MM; idx += blockDim.x) {
        float s = 0.f;
        #pragma unroll
        for (int k = 0; k < KSHOT; k++) s += base[(size_t)k * CC * MM + idx];
        sup[idx] = s * 0.2f;
    }
    __syncthreads();
    __shared__ float inv[MM];
    if (t < MM) {
        float ss = 0.f;
        for (int c = 0; c < CC; c++) { float v = sup[c * MM + t]; ss += v * v; }
        inv[t] = 1.0f / fmaxf(sqrtf(ss), 1e-8f);
    }
    __syncthreads();
    for (int idx = t; idx < CC * MM; idx += blockDim.x) {
        sup[idx] *= inv[idx % MM];
    }
}

// ---------------- kernel 2: query column inverse norms ----------------
__global__ void k_prep_query(const float* __restrict__ qx, float* __restrict__ ws) {
    int bq = blockIdx.x;
    int t = threadIdx.x;
    if (t >= MM) return;
    const float* base = qx + (size_t)bq * CC * MM;
    float ss = 0.f;
    for (int c = 0; c < CC; c++) { float v = base[c * MM + t]; ss += v * v; }
    ws[INVQ_OFF + bq * MM + t] = 1.0f / fmaxf(sqrtf(ss), 1e-8f);
}

// ---------------- kernel 3: 196x196 similarity GEMM + per-row per-class max/argmax ----------------
__global__ __launch_bounds__(256, 4) void k_sim(const float* __restrict__ qx,
                                                float* __restrict__ ws) {
    int blk = blockIdx.x;            // bq*NWAY + n
    int bq = blk / NWAY, n = blk % NWAY;
    int b = bq / QQ;
    const float* Abase = qx + (size_t)bq * CC * MM;                       // query (c, m)
    const float* Bbase = ws + SUP_OFF + (size_t)(b * NWAY + n) * CC * MM; // normalized support (c, m)

    __shared__ float At[CK][128];
    __shared__ float Bt[CK][128];
    __shared__ unsigned long long stat[MM];

    int t = threadIdx.x;
    int tr = t >> 4;        // 0..15 row-thread
    int tc = t & 15;        // 0..15 col-thread

    for (int i = t; i < MM; i += 256) stat[i] = 0ULL;
    __syncthreads();

    for (int ro = 0; ro <= 68; ro += 68)
    for (int co = 0; co <= 68; co += 68) {
        float acc[8][8];
        #pragma unroll
        for (int i = 0; i < 8; i++)
            #pragma unroll
            for (int j = 0; j < 8; j++) acc[i][j] = 0.f;

        for (int c0 = 0; c0 < CC; c0 += CK) {
            #pragma unroll
            for (int k = 0; k < 4; k++) {
                int idx = t + k * 256;           // 0..1023
                int ci = idx >> 5;               // 0..31
                int pos = (idx & 31) << 2;       // 0..124
                *(float4*)&At[ci][pos] = *(const float4*)&Abase[(size_t)(c0 + ci) * MM + ro + pos];
                *(float4*)&Bt[ci][pos] = *(const float4*)&Bbase[(size_t)(c0 + ci) * MM + co + pos];
            }
            __syncthreads();
            #pragma unroll 4
            for (int ci = 0; ci < CK; ci++) {
                float4 a0 = *(const float4*)&At[ci][tr * 8];
                float4 a1 = *(const float4*)&At[ci][tr * 8 + 4];
                float4 b0 = *(const float4*)&Bt[ci][tc * 8];
                float4 b1 = *(const float4*)&Bt[ci][tc * 8 + 4];
                float a[8] = {a0.x, a0.y, a0.z, a0.w, a1.x, a1.y, a1.z, a1.w};
                float bb[8] = {b0.x, b0.y, b0.z, b0.w, b1.x, b1.y, b1.z, b1.w};
                #pragma unroll
                for (int i = 0; i < 8; i++)
                    #pragma unroll
                    for (int j = 0; j < 8; j++)
                        acc[i][j] = fmaf(a[i], bb[j], acc[i][j]);
            }
            __syncthreads();
        }
        // per-thread row stats over its 8 cols (ascending col, strict > => first-index ties)
        #pragma unroll
        for (int i = 0; i < 8; i++) {
            int r = ro + tr * 8 + i;
            float bv = acc[i][0];
            int bj = co + tc * 8;
            #pragma unroll
            for (int j = 1; j < 8; j++) {
                int col = co + tc * 8 + j;
                if (acc[i][j] > bv) { bv = acc[i][j]; bj = col; }
            }
            unsigned int ub = __float_as_uint(bv);
            unsigned int su = (ub & 0x80000000u) ? ~ub : (ub | 0x80000000u); // sortable float
            unsigned long long key = ((unsigned long long)su << 32)
                                   | (unsigned long long)(0xFFFFFFFFu - (unsigned int)bj);
            atomicMax(&stat[r], key);
        }
        __syncthreads();
    }

    const float* invq = ws + INVQ_OFF + bq * MM;
    if (t < MM) {
        unsigned long long u = stat[t];
        unsigned int hi = (unsigned int)(u >> 32);
        unsigned int bits = (hi & 0x80000000u) ? (hi ^ 0x80000000u) : ~hi;
        float val = __uint_as_float(bits) * invq[t];
        int idx = (int)(0xFFFFFFFFu - (unsigned int)(u & 0xFFFFFFFFu));
        ws[CMAX_OFF + (size_t)blk * MM + t] = val;
        ((int*)ws)[CARG_OFF + (size_t)blk * MM + t] = idx;
    }
}

// ---------------- kernel 4: mutual-NN mask + predict + per-sample CE ----------------
__global__ void k_post(float* __restrict__ ws, const int* __restrict__ qy) {
    int bq = blockIdx.x;
    int t = threadIdx.x;
    __shared__ float cm[NWAY * MM];
    __shared__ int   ca[NWAY * MM];
    __shared__ float gmax[MM];
    __shared__ int   jst[MM];
    __shared__ int   msk[MM];
    __shared__ float pred[NWAY];

    const float* cmax = ws + CMAX_OFF + (size_t)bq * NWAY * MM;
    const int*   carg = (const int*)ws + CARG_OFF + (size_t)bq * NWAY * MM;
    for (int i = t; i < NWAY * MM; i += 256) { cm[i] = cmax[i]; ca[i] = carg[i]; }
    __syncthreads();

    if (t < MM) {       // cross-class combine: ascending n, strict > == n-major first-index
        float bv = cm[t];
        int bj = ca[t];
        for (int n = 1; n < NWAY; n++) {
            float v = cm[n * MM + t];
            if (v > bv) { bv = v; bj = n * MM + ca[n * MM + t]; }
        }
        gmax[t] = bv; jst[t] = bj;
    }
    __syncthreads();

    if (t < MM) {       // mutual-NN: winner of my support-column group (max gmax, min index)
        int myj = jst[t];
        float myv = gmax[t];
        int lose = 0;
        for (int m2 = 0; m2 < MM; m2++) {
            if (jst[m2] == myj &&
                (gmax[m2] > myv || (gmax[m2] == myv && m2 < t))) lose = 1;
        }
        msk[t] = !lose;
    }
    __syncthreads();

    if (t < NWAY) {
        float p = 0.f;
        for (int m = 0; m < MM; m++) if (msk[m]) p += cm[t * MM + m];
        pred[t] = 2.0f * p;   // TEMPERATURE = 2
    }
    __syncthreads();

    if (t == 0) {
        float pm = pred[0];
        for (int n = 1; n < NWAY; n++) pm = fmaxf(pm, pred[n]);
        float s = 0.f;
        for (int n = 0; n < NWAY; n++) s += expf(pred[n] - pm);
        float lse = pm + logf(s);
        int y = qy[bq];
        ws[SLOSS_OFF + bq] = (lse - pred[y]) * (1.0f / (BB * QQ));
    }
}

// ---------------- kernel 5: final reduce ----------------
__global__ void k_reduce(const float* __restrict__ ws, float* __restrict__ out) {
    int t = threadIdx.x;
    float s = 0.f;
    for (int i = t; i < BB * QQ; i += 256) s += ws[SLOSS_OFF + i];
    for (int off = 32; off > 0; off >>= 1) s += __shfl_down(s, off, 64);
    __shared__ float part[4];
    if ((t & 63) == 0) part[t >> 6] = s;
    __syncthreads();
    if (t == 0) out[0] = part[0] + part[1] + part[2] + part[3];
}

extern "C" void kernel_launch(void* const* d_in, const int* in_sizes, int n_in,
                              void* d_out, int out_size, void* d_ws, size_t ws_size,
                              hipStream_t stream) {
    const float* sx = (const float*)d_in[0];
    const int*   qy = (const int*)d_in[3];
    const float* qx = (const float*)d_in[2];
    float* out = (float*)d_out;
    float* ws  = (float*)d_ws;

    hipLaunchKernelGGL(k_prep_support, dim3(BB * NWAY), dim3(256), 0, stream, sx, ws);
    hipLaunchKernelGGL(k_prep_query,   dim3(BB * QQ),   dim3(256), 0, stream, qx, ws);
    hipLaunchKernelGGL(k_sim,          dim3(BB * QQ * NWAY), dim3(256), 0, stream, qx, ws);
    hipLaunchKernelGGL(k_post,         dim3(BB * QQ),   dim3(256), 0, stream, ws, qy);
    hipLaunchKernelGGL(k_reduce,       dim3(1),         dim3(256), 0, stream, ws, out);
}

// Round 2
// 760.355 us; speedup vs baseline: 3.0902x; 3.0902x over previous
//
#include <hip/hip_runtime.h>
#include <math.h>

#define NWAY 5
#define KSHOT 5
#define BB 4
#define QQ 75
#define CC 640
#define MM 196
#define BQ (BB*QQ)          // 300
#define MP 208              // padded rows & per-class col width (13 x 16 tiles)
#define NTOT 1040           // NWAY * MP
#define LDK 72              // LDS k-stride in halfs (64 + 8 pad -> 2-way-only bank alias)

// ---- ws layout (float offsets) ----
#define SUPF_OFF  0
#define SUPF_SZ   (BB*NWAY*CC*MM)            // 2,508,800
#define BPK_OFF   (SUPF_OFF + SUPF_SZ)
#define BPK_SZF   (BB*NTOT*CC/2)             // 1,331,200 floats (fp16 region)
#define APK_OFF   (BPK_OFF + BPK_SZF)
#define APK_SZF   (BQ*MP*CC/2)               // 19,968,000 floats (fp16 region)
#define INVQ_OFF  (APK_OFF + APK_SZF)
#define INVQ_SZ   (BQ*MM)                    // 58,800
#define GSTAT_OFF (INVQ_OFF + INVQ_SZ)       // even float offset -> 8B aligned
#define GSTAT_N   (BQ*NWAY*MP)               // 312,000 u64
#define SLOSS_OFF (GSTAT_OFF + 2*GSTAT_N)

typedef __attribute__((ext_vector_type(8))) _Float16 half8;
typedef __attribute__((ext_vector_type(4))) float floatx4;

// ---------------- k-shot mean ----------------
__global__ void k_mean(const float* __restrict__ sx, float* __restrict__ supf) {
    int blk = blockIdx.x;                 // 200 = 20 (b,n) * 10 c-chunks
    int bn = blk / 10, cc = blk % 10;
    int c0 = cc * 64;
    const float* base = sx + (size_t)bn * KSHOT * CC * MM;
    for (int idx = threadIdx.x; idx < 64 * MM; idx += 256) {
        int ci = idx / MM, m = idx - ci * MM;
        size_t off = (size_t)(c0 + ci) * MM + m;
        float s = 0.f;
        #pragma unroll
        for (int k = 0; k < KSHOT; k++) s += base[(size_t)k * CC * MM + off];
        supf[(size_t)bn * CC * MM + off] = s * 0.2f;
    }
}

// ---------------- normalize + transpose-pack support -> Bpk[b][col][c] fp16 ----------------
__global__ void k_packB(const float* __restrict__ supf, _Float16* __restrict__ Bpk) {
    int bn = blockIdx.x;                  // 20
    int b = bn / NWAY, n = bn % NWAY;
    int t = threadIdx.x;
    __shared__ float inv[MM];
    const float* S = supf + (size_t)bn * CC * MM;
    if (t < MM) {
        float ss = 0.f;
        for (int c = 0; c < CC; c++) { float v = S[(size_t)c * MM + t]; ss += v * v; }
        inv[t] = 1.0f / fmaxf(sqrtf(ss), 1e-8f);
    }
    __syncthreads();
    _Float16* out = Bpk + ((size_t)b * NTOT + (size_t)n * MP) * CC;
    for (int odx = t; odx < MP * CC; odx += 256) {
        int mm = odx / CC, c = odx - mm * CC;
        float v = (mm < MM) ? S[(size_t)c * MM + mm] * inv[mm] : 0.f;
        out[(size_t)mm * CC + c] = (_Float16)v;
    }
}

// ---------------- transpose-pack query -> Apk[bq][m][c] fp16 ----------------
__global__ void k_pack_A(const float* __restrict__ qx, _Float16* __restrict__ Apk) {
    int blk = blockIdx.x;                 // 6000 = 300 bq * 20 c-chunks
    int bq = blk / 20, cc = blk % 20;
    int c0 = cc * 32;
    __shared__ float T[MM * 33];
    int t = threadIdx.x;
    const float* Q = qx + (size_t)bq * CC * MM;
    for (int idx = t; idx < 32 * MM; idx += 256) {
        int ci = idx / MM, m = idx - ci * MM;
        T[m * 33 + ci] = Q[(size_t)(c0 + ci) * MM + m];
    }
    __syncthreads();
    _Float16* out = Apk + (size_t)bq * MP * CC;
    for (int odx = t; odx < MP * 32; odx += 256) {
        int mm = odx >> 5, cj = odx & 31;
        float v = (mm < MM) ? T[mm * 33 + cj] : 0.f;
        out[(size_t)mm * CC + c0 + cj] = (_Float16)v;
    }
}

// ---------------- query column inverse norms ----------------
__global__ void k_prep_query(const float* __restrict__ qx, float* __restrict__ invq) {
    int bq = blockIdx.x, t = threadIdx.x;
    if (t >= MM) return;
    const float* base = qx + (size_t)bq * CC * MM;
    float ss = 0.f;
    for (int c = 0; c < CC; c++) { float v = base[(size_t)c * MM + t]; ss += v * v; }
    invq[bq * MM + t] = 1.0f / fmaxf(sqrtf(ss), 1e-8f);
}

// ---------------- MFMA similarity + fused row stats ----------------
template<int MT>
__device__ __forceinline__ void sim_body(
    int mbase, int t, int lane, int bq, int b, int g,
    const _Float16* __restrict__ Apk, const _Float16* __restrict__ Bpk,
    unsigned long long* __restrict__ gstat,
    _Float16* At, _Float16* Bt)
{
    floatx4 acc[MT][5];
    #pragma unroll
    for (int i = 0; i < MT; i++)
        #pragma unroll
        for (int j = 0; j < 5; j++) acc[i][j] = (floatx4){0.f, 0.f, 0.f, 0.f};

    const _Float16* Abase = Apk + (size_t)bq * MP * CC;
    const _Float16* Bbase = Bpk + ((size_t)b * NTOT + (size_t)g * 80) * CC;

    for (int c0 = 0; c0 < CC; c0 += 64) {
        #pragma unroll
        for (int p = 0; p < 7; p++) {
            int idx = t + p * 256;
            if (idx < MP * 8) {
                int m = idx >> 3, sub = idx & 7;
                *(float4*)&At[m * LDK + sub * 8] =
                    *(const float4*)&Abase[(size_t)m * CC + c0 + sub * 8];
            }
        }
        #pragma unroll
        for (int p = 0; p < 3; p++) {
            int idx = t + p * 256;
            if (idx < 80 * 8) {
                int jl = idx >> 3, sub = idx & 7;
                *(float4*)&Bt[jl * LDK + sub * 8] =
                    *(const float4*)&Bbase[(size_t)jl * CC + c0 + sub * 8];
            }
        }
        __syncthreads();
        #pragma unroll
        for (int ks = 0; ks < 2; ks++) {
            int lk = ks * 32 + (lane >> 4) * 8;
            int l15 = lane & 15;
            half8 af[MT], bf[5];
            #pragma unroll
            for (int i = 0; i < MT; i++)
                af[i] = *(const half8*)&At[((mbase + i) * 16 + l15) * LDK + lk];
            #pragma unroll
            for (int j = 0; j < 5; j++)
                bf[j] = *(const half8*)&Bt[(j * 16 + l15) * LDK + lk];
            #pragma unroll
            for (int i = 0; i < MT; i++)
                #pragma unroll
                for (int j = 0; j < 5; j++)
                    acc[i][j] = __builtin_amdgcn_mfma_f32_16x16x32_f16(af[i], bf[j], acc[i][j], 0, 0, 0);
        }
        __syncthreads();
    }

    // epilogue: per-row per-class max/argmax -> packed u64 global atomicMax
    int l15 = lane & 15, q = lane >> 4;
    #pragma unroll
    for (int i = 0; i < MT; i++)
        #pragma unroll
        for (int j = 0; j < 5; j++) {
            int gnt = g * 5 + j;
            int cls = gnt / 13;
            int ms = (gnt - cls * 13) * 16 + l15;
            #pragma unroll
            for (int r = 0; r < 4; r++) {
                float v = acc[i][j][r];
                unsigned int ub = __float_as_uint(v);
                unsigned int su = (ub & 0x80000000u) ? ~ub : (ub | 0x80000000u);
                unsigned long long key = (ms < MM)
                    ? (((unsigned long long)su << 32) |
                       (unsigned long long)(0xFFFFFFFFu - (unsigned int)ms))
                    : 0ULL;
                #pragma unroll
                for (int s = 1; s < 16; s <<= 1) {
                    unsigned long long o = __shfl_xor(key, s, 64);
                    if (o > key) key = o;
                }
                int m = (mbase + i) * 16 + q * 4 + r;
                if (l15 == 0 && m < MM)
                    atomicMax(&gstat[((size_t)bq * NWAY + cls) * MP + m], key);
            }
        }
}

__global__ __launch_bounds__(256, 2) void k_sim(
    const _Float16* __restrict__ Apk, const _Float16* __restrict__ Bpk,
    unsigned long long* __restrict__ gstat)
{
    __shared__ __align__(16) _Float16 At[MP * LDK];   // 29,952 B
    __shared__ __align__(16) _Float16 Bt[80 * LDK];   // 11,520 B
    int t = threadIdx.x, lane = t & 63, w = t >> 6;
    int bq = blockIdx.x, g = blockIdx.y, b = bq / QQ;
    if (w == 0) sim_body<4>(0, t, lane, bq, b, g, Apk, Bpk, gstat, At, Bt);
    else        sim_body<3>(1 + w * 3, t, lane, bq, b, g, Apk, Bpk, gstat, At, Bt);
}

// ---------------- mutual-NN mask + predict + per-sample CE ----------------
__global__ void k_post(const unsigned long long* __restrict__ gstat,
                       const float* __restrict__ invq,
                       float* __restrict__ sloss, const int* __restrict__ qy) {
    int bq = blockIdx.x;
    int t = threadIdx.x;
    __shared__ float cm[NWAY * MM];
    __shared__ int   ca[NWAY * MM];
    __shared__ float gmax[MM];
    __shared__ int   jst[MM];
    __shared__ int   msk[MM];
    __shared__ float pred[NWAY];

    for (int i = t; i < NWAY * MM; i += 256) {
        int n = i / MM, m = i - n * MM;
        unsigned long long key = gstat[((size_t)bq * NWAY + n) * MP + m];
        unsigned int hi = (unsigned int)(key >> 32);
        unsigned int bits = (hi & 0x80000000u) ? (hi ^ 0x80000000u) : ~hi;
        cm[i] = __uint_as_float(bits) * invq[bq * MM + m];
        ca[i] = (int)(0xFFFFFFFFu - (unsigned int)(key & 0xFFFFFFFFu));
    }
    __syncthreads();

    if (t < MM) {       // cross-class combine: ascending n, strict > == n-major first-index
        float bv = cm[t];
        int bj = ca[t];
        for (int n = 1; n < NWAY; n++) {
            float v = cm[n * MM + t];
            if (v > bv) { bv = v; bj = n * MM + ca[n * MM + t]; }
        }
        gmax[t] = bv; jst[t] = bj;
    }
    __syncthreads();

    if (t < MM) {       // mutual-NN: winner of my support-column group (max gmax, min index)
        int myj = jst[t];
        float myv = gmax[t];
        int lose = 0;
        for (int m2 = 0; m2 < MM; m2++) {
            if (jst[m2] == myj &&
                (gmax[m2] > myv || (gmax[m2] == myv && m2 < t))) lose = 1;
        }
        msk[t] = !lose;
    }
    __syncthreads();

    if (t < NWAY) {
        float p = 0.f;
        for (int m = 0; m < MM; m++) if (msk[m]) p += cm[t * MM + m];
        pred[t] = 2.0f * p;   // TEMPERATURE = 2
    }
    __syncthreads();

    if (t == 0) {
        float pm = pred[0];
        for (int n = 1; n < NWAY; n++) pm = fmaxf(pm, pred[n]);
        float s = 0.f;
        for (int n = 0; n < NWAY; n++) s += expf(pred[n] - pm);
        float lse = pm + logf(s);
        int y = qy[bq];
        sloss[bq] = (lse - pred[y]) * (1.0f / (BB * QQ));
    }
}

// ---------------- final reduce ----------------
__global__ void k_reduce(const float* __restrict__ sloss, float* __restrict__ out) {
    int t = threadIdx.x;
    float s = 0.f;
    for (int i = t; i < BQ; i += 256) s += sloss[i];
    for (int off = 32; off > 0; off >>= 1) s += __shfl_down(s, off, 64);
    __shared__ float part[4];
    if ((t & 63) == 0) part[t >> 6] = s;
    __syncthreads();
    if (t == 0) out[0] = part[0] + part[1] + part[2] + part[3];
}

extern "C" void kernel_launch(void* const* d_in, const int* in_sizes, int n_in,
                              void* d_out, int out_size, void* d_ws, size_t ws_size,
                              hipStream_t stream) {
    const float* sx = (const float*)d_in[0];
    const float* qx = (const float*)d_in[2];
    const int*   qy = (const int*)d_in[3];
    float* out = (float*)d_out;
    float* ws  = (float*)d_ws;

    float* supf = ws + SUPF_OFF;
    _Float16* Bpk = (_Float16*)(ws + BPK_OFF);
    _Float16* Apk = (_Float16*)(ws + APK_OFF);
    float* invq = ws + INVQ_OFF;
    unsigned long long* gstat = (unsigned long long*)(ws + GSTAT_OFF);
    float* sloss = ws + SLOSS_OFF;

    hipMemsetAsync(gstat, 0, (size_t)GSTAT_N * 8, stream);
    hipLaunchKernelGGL(k_mean,       dim3(200),      dim3(256), 0, stream, sx, supf);
    hipLaunchKernelGGL(k_packB,      dim3(20),       dim3(256), 0, stream, supf, Bpk);
    hipLaunchKernelGGL(k_pack_A,     dim3(6000),     dim3(256), 0, stream, qx, Apk);
    hipLaunchKernelGGL(k_prep_query, dim3(300),      dim3(256), 0, stream, qx, invq);
    hipLaunchKernelGGL(k_sim,        dim3(300, 13),  dim3(256), 0, stream, Apk, Bpk, gstat);
    hipLaunchKernelGGL(k_post,       dim3(300),      dim3(256), 0, stream, gstat, invq, sloss, qy);
    hipLaunchKernelGGL(k_reduce,     dim3(1),        dim3(256), 0, stream, sloss, out);
}

// Round 3
// 586.237 us; speedup vs baseline: 4.0080x; 1.2970x over previous
//
#include <hip/hip_runtime.h>
#include <math.h>

#define NWAY 5
#define KSHOT 5
#define BB 4
#define QQ 75
#define CC 640
#define MM 196
#define BQ (BB*QQ)          // 300
#define MP 208              // padded rows & per-class col width (13 x 16 tiles)
#define NTOT 1040           // NWAY * MP

// ---- ws layout (float offsets) ----
#define BPK_OFF   0
#define BPK_SZF   (BB*NTOT*CC/2)            // 1,331,200 (fp16 region)
#define APK_OFF   (BPK_OFF + BPK_SZF)
#define APK_SZF   (BQ*MP*CC/2)              // 19,968,000 (fp16 region)
#define SUPF_OFF  (APK_OFF + APK_SZF)
#define SUPF_SZ   (BB*NWAY*CC*MM)           // 2,508,800
#define GSTAT_OFF (SUPF_OFF + SUPF_SZ)      // even -> 8B aligned
#define GSTAT_N   (BQ*NWAY*MP)              // 312,000 u64
#define NRMS_OFF  (GSTAT_OFF + 2*GSTAT_N)
#define NRMS_SZ   (BB*NWAY*MM)              // 3,920
#define NRMQ_OFF  (NRMS_OFF + NRMS_SZ)
#define NRMQ_SZ   (BQ*MM)                   // 58,800
#define INVS_OFF  (NRMQ_OFF + NRMQ_SZ)
#define INVQ_OFF  (INVS_OFF + NRMS_SZ)
#define SLOSS_OFF (INVQ_OFF + NRMQ_SZ)

typedef __attribute__((ext_vector_type(8))) _Float16 half8;
typedef __attribute__((ext_vector_type(4))) float floatx4;

// ---------------- k-shot mean + support column sumsq partials ----------------
__global__ void k_mean(const float* __restrict__ sx, float* __restrict__ supf,
                       float* __restrict__ nrms) {
    int blk = blockIdx.x;                 // 200 = 20 (b,n) * 10 c-chunks
    int bn = blk / 10, cc = blk % 10;
    int c0 = cc * 64;
    __shared__ float st[64 * MM];         // 50,176 B
    const float* base = sx + (size_t)bn * KSHOT * CC * MM;
    int t = threadIdx.x;
    for (int idx = t; idx < 64 * MM; idx += 256) {
        size_t off = (size_t)c0 * MM + idx;
        float s = 0.f;
        #pragma unroll
        for (int k = 0; k < KSHOT; k++) s += base[(size_t)k * CC * MM + off];
        s *= 0.2f;
        supf[(size_t)bn * CC * MM + off] = s;
        st[idx] = s;
    }
    __syncthreads();
    if (t < MM) {
        float ss = 0.f;
        for (int ci = 0; ci < 64; ci++) { float v = st[ci * MM + t]; ss += v * v; }
        atomicAdd(&nrms[bn * MM + t], ss);
    }
}

// ---------------- transpose-pack query -> Apk[bq][m][c] fp16 + query sumsq partials ----------------
__global__ void k_pack_A(const float* __restrict__ qx, _Float16* __restrict__ Apk,
                         float* __restrict__ nrmq) {
    int blk = blockIdx.x;                 // 6000 = 300 bq * 20 c-chunks
    int bq = blk / 20, cc = blk % 20;
    int c0 = cc * 32;
    __shared__ float T[MM * 33];
    int t = threadIdx.x;
    const float* Q = qx + (size_t)bq * CC * MM;
    for (int idx = t; idx < 32 * MM; idx += 256) {
        int ci = idx / MM, m = idx - ci * MM;
        T[m * 33 + ci] = Q[(size_t)(c0 + ci) * MM + m];
    }
    __syncthreads();
    _Float16* out = Apk + (size_t)bq * MP * CC;
    for (int odx = t; odx < MP * 32; odx += 256) {
        int mm = odx >> 5, cj = odx & 31;
        float v = (mm < MM) ? T[mm * 33 + cj] : 0.f;
        out[(size_t)mm * CC + c0 + cj] = (_Float16)v;
    }
    if (t < MM) {
        float ss = 0.f;
        #pragma unroll 8
        for (int cj = 0; cj < 32; cj++) { float v = T[t * 33 + cj]; ss += v * v; }
        atomicAdd(&nrmq[bq * MM + t], ss);
    }
}

// ---------------- sumsq -> 1/max(sqrt,eps) for both support and query ----------------
__global__ void k_inv(const float* __restrict__ nrm, float* __restrict__ inv, int n) {
    int i = blockIdx.x * 256 + threadIdx.x;
    if (i < n) inv[i] = 1.0f / fmaxf(sqrtf(nrm[i]), 1e-8f);
}

// ---------------- normalize + transpose-pack support -> Bpk[b][col][c] fp16 ----------------
__global__ void k_packB(const float* __restrict__ supf, const float* __restrict__ invs,
                        _Float16* __restrict__ Bpk) {
    int blk = blockIdx.x;                 // 200 = 20 (b,n) * 10 c-chunks
    int bn = blk / 10, cc = blk % 10;
    int b = bn / NWAY, n = bn % NWAY;
    int c0 = cc * 64;
    __shared__ float T[64 * 197];         // 50,432 B
    int t = threadIdx.x;
    const float* S = supf + (size_t)bn * CC * MM;
    for (int idx = t; idx < 64 * MM; idx += 256) {
        int ci = idx / MM, m = idx - ci * MM;
        T[ci * 197 + m] = S[(size_t)(c0 + ci) * MM + m];
    }
    __syncthreads();
    _Float16* out = Bpk + ((size_t)b * NTOT + (size_t)n * MP) * CC;
    for (int odx = t; odx < MP * 64; odx += 256) {
        int mm = odx >> 6, ci = odx & 63;
        float v = (mm < MM) ? T[ci * 197 + mm] * invs[bn * MM + mm] : 0.f;
        out[(size_t)mm * CC + c0 + ci] = (_Float16)v;
    }
}

// ---------------- MFMA similarity + fused row stats ----------------
// LDS: A 208 rows x 64 halfs (1664 16B-chunks), B 80 rows x 64 halfs (640 chunks).
// Chunk slot j of row m holds global chunk (j ^ (m&7)) -> ds_read_b128 is 2-way aliased (free).
template<int MT>
__device__ __forceinline__ void sim_body(
    int mbase, int t, int lane, int w, int bq, int b, int g,
    const _Float16* __restrict__ Apk, const _Float16* __restrict__ Bpk,
    unsigned long long* __restrict__ gstat, _Float16* Lds)
{
    floatx4 acc[MT][5];
    #pragma unroll
    for (int i = 0; i < MT; i++)
        #pragma unroll
        for (int j = 0; j < 5; j++) acc[i][j] = (floatx4){0.f, 0.f, 0.f, 0.f};

    const _Float16* Ab = Apk + (size_t)bq * MP * CC;
    const _Float16* Bb = Bpk + ((size_t)b * NTOT + (size_t)g * 80) * CC;
    int q = lane >> 4, l15 = lane & 15;

    for (int c0 = 0; c0 < CC; c0 += 64) {
        #pragma unroll
        for (int p = 0; p < 9; p++) {
            int inst = w * 9 + p;             // 0..35, uniform per wave-instruction
            int chunkbase = inst << 6;
            int chunk = chunkbase + lane;
            const _Float16* src;
            if (chunkbase < 1664) {           // A instruction (26 insts)
                int m = chunk >> 3, j = chunk & 7;
                src = Ab + (size_t)m * CC + c0 + ((j ^ (m & 7)) << 3);
            } else {                          // B instruction (10 insts)
                int cbk = chunk - 1664;
                int jl = cbk >> 3, j = cbk & 7;
                src = Bb + (size_t)jl * CC + c0 + ((j ^ (jl & 7)) << 3);
            }
            __builtin_amdgcn_global_load_lds(
                (const __attribute__((address_space(1))) void*)src,
                (__attribute__((address_space(3))) void*)(Lds + ((size_t)chunkbase << 3)),
                16, 0, 0);
        }
        __syncthreads();
        #pragma unroll
        for (int ks = 0; ks < 2; ks++) {
            int cj = ks * 4 + q;              // 16B chunk index within row, 0..7
            half8 af[MT], bf[5];
            #pragma unroll
            for (int i = 0; i < MT; i++) {
                int m = (mbase + i) * 16 + l15;
                af[i] = *(const half8*)&Lds[(m << 6) + ((cj ^ (m & 7)) << 3)];
            }
            #pragma unroll
            for (int j = 0; j < 5; j++) {
                int jl = j * 16 + l15;
                bf[j] = *(const half8*)&Lds[13312 + (jl << 6) + ((cj ^ (jl & 7)) << 3)];
            }
            #pragma unroll
            for (int i = 0; i < MT; i++)
                #pragma unroll
                for (int j = 0; j < 5; j++)
                    acc[i][j] = __builtin_amdgcn_mfma_f32_16x16x32_f16(af[i], bf[j], acc[i][j], 0, 0, 0);
        }
        __syncthreads();
    }

    // epilogue: per-row per-class max/argmax -> packed u64 global atomicMax
    #pragma unroll
    for (int i = 0; i < MT; i++)
        #pragma unroll
        for (int j = 0; j < 5; j++) {
            int gnt = g * 5 + j;
            int cls = gnt / 13;
            int ms = (gnt - cls * 13) * 16 + l15;
            #pragma unroll
            for (int r = 0; r < 4; r++) {
                float v = acc[i][j][r];
                unsigned int ub = __float_as_uint(v);
                unsigned int su = (ub & 0x80000000u) ? ~ub : (ub | 0x80000000u);
                unsigned long long key = (ms < MM)
                    ? (((unsigned long long)su << 32) |
                       (unsigned long long)(0xFFFFFFFFu - (unsigned int)ms))
                    : 0ULL;
                #pragma unroll
                for (int s = 1; s < 16; s <<= 1) {
                    unsigned long long o = __shfl_xor(key, s, 64);
                    if (o > key) key = o;
                }
                int m = (mbase + i) * 16 + q * 4 + r;
                if (l15 == 0 && m < MM)
                    atomicMax(&gstat[((size_t)bq * NWAY + cls) * MP + m], key);
            }
        }
}

__global__ __launch_bounds__(256, 4) void k_sim(
    const _Float16* __restrict__ Apk, const _Float16* __restrict__ Bpk,
    unsigned long long* __restrict__ gstat)
{
    __shared__ __align__(16) _Float16 Lds[18432];   // 36,864 B -> 4 blocks/CU
    int id = blockIdx.x;
    int x = id & 7, s = id >> 3;      // XCD swizzle: all 13 g of one bq -> same XCD
    int g = s % 13;
    int bq = x + ((s / 13) << 3);
    if (bq >= BQ) return;
    int b = bq / QQ;
    int t = threadIdx.x, lane = t & 63, w = t >> 6;
    if (w == 0) sim_body<4>(0, t, lane, w, bq, b, g, Apk, Bpk, gstat, Lds);
    else        sim_body<3>(1 + w * 3, t, lane, w, bq, b, g, Apk, Bpk, gstat, Lds);
}

// ---------------- mutual-NN mask + predict + per-sample CE ----------------
__global__ void k_post(const unsigned long long* __restrict__ gstat,
                       const float* __restrict__ invq,
                       float* __restrict__ sloss, const int* __restrict__ qy) {
    int bq = blockIdx.x;
    int t = threadIdx.x;
    __shared__ float cm[NWAY * MM];
    __shared__ int   ca[NWAY * MM];
    __shared__ float gmax[MM];
    __shared__ int   jst[MM];
    __shared__ int   msk[MM];
    __shared__ float pred[NWAY];

    for (int i = t; i < NWAY * MM; i += 256) {
        int n = i / MM, m = i - n * MM;
        unsigned long long key = gstat[((size_t)bq * NWAY + n) * MP + m];
        unsigned int hi = (unsigned int)(key >> 32);
        unsigned int bits = (hi & 0x80000000u) ? (hi ^ 0x80000000u) : ~hi;
        cm[i] = __uint_as_float(bits) * invq[bq * MM + m];
        ca[i] = (int)(0xFFFFFFFFu - (unsigned int)(key & 0xFFFFFFFFu));
    }
    __syncthreads();

    if (t < MM) {       // cross-class combine: ascending n, strict > == n-major first-index
        float bv = cm[t];
        int bj = ca[t];
        for (int n = 1; n < NWAY; n++) {
            float v = cm[n * MM + t];
            if (v > bv) { bv = v; bj = n * MM + ca[n * MM + t]; }
        }
        gmax[t] = bv; jst[t] = bj;
    }
    __syncthreads();

    if (t < MM) {       // mutual-NN: winner of my support-column group (max gmax, min index)
        int myj = jst[t];
        float myv = gmax[t];
        int lose = 0;
        for (int m2 = 0; m2 < MM; m2++) {
            if (jst[m2] == myj &&
                (gmax[m2] > myv || (gmax[m2] == myv && m2 < t))) lose = 1;
        }
        msk[t] = !lose;
    }
    __syncthreads();

    if (t < NWAY) {
        float p = 0.f;
        for (int m = 0; m < MM; m++) if (msk[m]) p += cm[t * MM + m];
        pred[t] = 2.0f * p;   // TEMPERATURE = 2
    }
    __syncthreads();

    if (t == 0) {
        float pm = pred[0];
        for (int n = 1; n < NWAY; n++) pm = fmaxf(pm, pred[n]);
        float s = 0.f;
        for (int n = 0; n < NWAY; n++) s += expf(pred[n] - pm);
        float lse = pm + logf(s);
        int y = qy[bq];
        sloss[bq] = (lse - pred[y]) * (1.0f / (BB * QQ));
    }
}

// ---------------- final reduce ----------------
__global__ void k_reduce(const float* __restrict__ sloss, float* __restrict__ out) {
    int t = threadIdx.x;
    float s = 0.f;
    for (int i = t; i < BQ; i += 256) s += sloss[i];
    for (int off = 32; off > 0; off >>= 1) s += __shfl_down(s, off, 64);
    __shared__ float part[4];
    if ((t & 63) == 0) part[t >> 6] = s;
    __syncthreads();
    if (t == 0) out[0] = part[0] + part[1] + part[2] + part[3];
}

extern "C" void kernel_launch(void* const* d_in, const int* in_sizes, int n_in,
                              void* d_out, int out_size, void* d_ws, size_t ws_size,
                              hipStream_t stream) {
    const float* sx = (const float*)d_in[0];
    const float* qx = (const float*)d_in[2];
    const int*   qy = (const int*)d_in[3];
    float* out = (float*)d_out;
    float* ws  = (float*)d_ws;

    _Float16* Bpk = (_Float16*)(ws + BPK_OFF);
    _Float16* Apk = (_Float16*)(ws + APK_OFF);
    float* supf = ws + SUPF_OFF;
    unsigned long long* gstat = (unsigned long long*)(ws + GSTAT_OFF);
    float* nrms = ws + NRMS_OFF;
    float* nrmq = ws + NRMQ_OFF;
    float* invs = ws + INVS_OFF;
    float* invq = ws + INVQ_OFF;
    float* sloss = ws + SLOSS_OFF;

    // zero gstat + nrms + nrmq in one shot (contiguous)
    hipMemsetAsync(gstat, 0, (size_t)(2 * GSTAT_N + NRMS_SZ + NRMQ_SZ) * 4, stream);
    hipLaunchKernelGGL(k_mean,   dim3(200),  dim3(256), 0, stream, sx, supf, nrms);
    hipLaunchKernelGGL(k_pack_A, dim3(6000), dim3(256), 0, stream, qx, Apk, nrmq);
    hipLaunchKernelGGL(k_inv,    dim3((NRMS_SZ + NRMQ_SZ + 255) / 256), dim3(256), 0, stream,
                       nrms, invs, NRMS_SZ + NRMQ_SZ);
    hipLaunchKernelGGL(k_packB,  dim3(200),  dim3(256), 0, stream, supf, invs, Bpk);
    hipLaunchKernelGGL(k_sim,    dim3(8 * 38 * 13), dim3(256), 0, stream, Apk, Bpk, gstat);
    hipLaunchKernelGGL(k_post,   dim3(300),  dim3(256), 0, stream, gstat, invq, sloss, qy);
    hipLaunchKernelGGL(k_reduce, dim3(1),    dim3(256), 0, stream, sloss, out);
}

// Round 4
// 487.317 us; speedup vs baseline: 4.8216x; 1.2030x over previous
//
#include <hip/hip_runtime.h>
#include <math.h>

#define NWAY 5
#define KSHOT 5
#define BB 4
#define QQ 75
#define CC 640
#define MM 196
#define BQ (BB*QQ)          // 300
#define MP 208              // padded A rows per bq
#define NCOL 1024           // padded flat col space (980 real)
#define NREAL 980

// ---- ws layout (float offsets) ----
#define BPK_OFF   0
#define BPK_SZF   (BB*NCOL*CC/2)            // 1,310,720 (fp16 region)
#define APK_OFF   (BPK_OFF + BPK_SZF)
#define APK_SZF   (BQ*MP*CC/2)              // 19,968,000 (fp16 region)
#define SUPF_OFF  (APK_OFF + APK_SZF)
#define SUPF_SZ   (BB*NWAY*CC*MM)           // 2,508,800
#define GSTAT_OFF (SUPF_OFF + SUPF_SZ)      // even -> 8B aligned
#define GSTAT_N   (BQ*NWAY*MP)              // 312,000 u64
#define NRMS_OFF  (GSTAT_OFF + 2*GSTAT_N)
#define NRMS_SZ   (BB*NWAY*MM)              // 3,920
#define NRMQ_OFF  (NRMS_OFF + NRMS_SZ)
#define NRMQ_SZ   (BQ*MM)                   // 58,800
#define INVS_OFF  (NRMQ_OFF + NRMQ_SZ)
#define INVQ_OFF  (INVS_OFF + NRMS_SZ)
#define SLOSS_OFF (INVQ_OFF + NRMQ_SZ)

typedef __attribute__((ext_vector_type(8))) _Float16 half8;
typedef __attribute__((ext_vector_type(4))) float floatx4;

// ---------------- k-shot mean + support column sumsq partials ----------------
__global__ void k_mean(const float* __restrict__ sx, float* __restrict__ supf,
                       float* __restrict__ nrms) {
    int blk = blockIdx.x;                 // 200 = 20 (b,n) * 10 c-chunks
    int bn = blk / 10, cc = blk % 10;
    int c0 = cc * 64;
    __shared__ float st[64 * MM];         // 50,176 B
    const float* base = sx + (size_t)bn * KSHOT * CC * MM;
    int t = threadIdx.x;
    for (int idx = t; idx < 64 * MM; idx += 256) {
        size_t off = (size_t)c0 * MM + idx;
        float s = 0.f;
        #pragma unroll
        for (int k = 0; k < KSHOT; k++) s += base[(size_t)k * CC * MM + off];
        s *= 0.2f;
        supf[(size_t)bn * CC * MM + off] = s;
        st[idx] = s;
    }
    __syncthreads();
    if (t < MM) {
        float ss = 0.f;
        for (int ci = 0; ci < 64; ci++) { float v = st[ci * MM + t]; ss += v * v; }
        atomicAdd(&nrms[bn * MM + t], ss);
    }
}

// ---------------- transpose-pack query -> Apk[bq][m][c] fp16 + query sumsq partials ----------------
__global__ void k_pack_A(const float* __restrict__ qx, _Float16* __restrict__ Apk,
                         float* __restrict__ nrmq) {
    int blk = blockIdx.x;                 // 3000 = 300 bq * 10 c-chunks
    int bq = blk / 10, cc = blk % 10;
    int c0 = cc * 64;
    __shared__ float T[64 * 197];         // 50,432 B
    int t = threadIdx.x;
    const float* Q = qx + (size_t)bq * CC * MM;
    for (int idx = t; idx < 64 * MM; idx += 256) {
        int ci = idx / MM, m = idx - ci * MM;
        T[ci * 197 + m] = Q[(size_t)(c0 + ci) * MM + m];
    }
    __syncthreads();
    _Float16* out = Apk + (size_t)bq * MP * CC;
    int mloc = t >> 3, cj8 = t & 7;       // 32 rows x 8 col-groups per pass
    #pragma unroll
    for (int r = 0; r < 7; r++) {
        int mm = r * 32 + mloc;
        if (mm < MP) {
            half8 v;
            #pragma unroll
            for (int k = 0; k < 8; k++) {
                float f = (mm < MM) ? T[(cj8 * 8 + k) * 197 + mm] : 0.f;
                v[k] = (_Float16)f;
            }
            *(half8*)&out[(size_t)mm * CC + c0 + cj8 * 8] = v;
        }
    }
    if (t < MM) {
        float ss = 0.f;
        for (int ci = 0; ci < 64; ci++) { float v = T[ci * 197 + t]; ss += v * v; }
        atomicAdd(&nrmq[bq * MM + t], ss);
    }
}

// ---------------- sumsq -> 1/max(sqrt,eps) ----------------
__global__ void k_inv(const float* __restrict__ nrm, float* __restrict__ inv, int n) {
    int i = blockIdx.x * 256 + threadIdx.x;
    if (i < n) inv[i] = 1.0f / fmaxf(sqrtf(nrm[i]), 1e-8f);
}

// ---------------- normalize + transpose-pack support -> Bpk[b][col=n*196+ms][c] fp16 ----------------
__global__ void k_packB(const float* __restrict__ supf, const float* __restrict__ invs,
                        _Float16* __restrict__ Bpk) {
    int blk = blockIdx.x;                 // 200 = 20 (b,n) * 10 c-chunks
    int bn = blk / 10, cc = blk % 10;
    int b = bn / NWAY, n = bn % NWAY;
    int c0 = cc * 64;
    __shared__ float T[64 * 197];
    int t = threadIdx.x;
    const float* S = supf + (size_t)bn * CC * MM;
    for (int idx = t; idx < 64 * MM; idx += 256) {
        int ci = idx / MM, m = idx - ci * MM;
        T[ci * 197 + m] = S[(size_t)(c0 + ci) * MM + m];
    }
    __syncthreads();
    _Float16* out = Bpk + ((size_t)b * NCOL + (size_t)n * MM) * CC;
    int mloc = t >> 3, cj8 = t & 7;
    #pragma unroll
    for (int r = 0; r < 7; r++) {
        int mm = r * 32 + mloc;
        if (mm < MM) {
            float inv = invs[bn * MM + mm];
            half8 v;
            #pragma unroll
            for (int k = 0; k < 8; k++)
                v[k] = (_Float16)(T[(cj8 * 8 + k) * 197 + mm] * inv);
            *(half8*)&out[(size_t)mm * CC + c0 + cj8 * 8] = v;
        }
    }
}

// ---------------- MFMA similarity: 128x128 block (m97 shape) + segmented epilogue ----------------
// LDS: A 128 rows x 64 halfs (chunks 0-1023), B 128 cols x 64 halfs (chunks 1024-2047).
// Chunk slot j of row m holds global chunk j^(m&7) -> ds_read_b128 2-way aliased (free).
__global__ __launch_bounds__(256, 3) void k_sim(
    const _Float16* __restrict__ Apk, const _Float16* __restrict__ Bpk,
    unsigned long long* __restrict__ gstat)
{
    __shared__ __align__(16) _Float16 Lds[16384];   // 32,768 B
    int id = blockIdx.x;
    int x = id & 7, s = id >> 3;          // XCD swizzle: 16 blocks of one bq -> same XCD
    int sub = s & 15, bqg = s >> 4;
    int bq = x + (bqg << 3);
    if (bq >= BQ) return;
    int mblk = sub >> 3, cblk = sub & 7;
    int b = bq / QQ;

    int t = threadIdx.x, lane = t & 63, w = t >> 6;
    int q = lane >> 4, l15 = lane & 15;
    int wi = w >> 1, wj = w & 1;

    const _Float16* Ab = Apk + (size_t)bq * MP * CC + (size_t)(mblk * 128) * CC;
    const _Float16* Bb = Bpk + ((size_t)b * NCOL + (size_t)(cblk * 128)) * CC;

    // per-lane staging source pointers (wave-uniform A/B split: w0,w1 -> A, w2,w3 -> B)
    const _Float16* srcp[8];
    #pragma unroll
    for (int p = 0; p < 8; p++) {
        int chunk = (w * 8 + p) * 64 + lane;
        if (chunk < 1024) {
            int m = chunk >> 3, j = chunk & 7;
            srcp[p] = Ab + (size_t)m * CC + ((j ^ (m & 7)) << 3);
        } else {
            int cb = chunk - 1024;
            int jl = cb >> 3, j = cb & 7;
            srcp[p] = Bb + (size_t)jl * CC + ((j ^ (jl & 7)) << 3);
        }
    }

    // fragment LDS offsets (halfs)
    int arow[4], asw[4], brow[4], bsw[4];
    #pragma unroll
    for (int i = 0; i < 4; i++) {
        int m = wi * 64 + i * 16 + l15;
        arow[i] = m * 64; asw[i] = m & 7;
        int jl = wj * 64 + i * 16 + l15;
        brow[i] = 8192 + jl * 64; bsw[i] = jl & 7;
    }

    floatx4 acc[4][4];
    #pragma unroll
    for (int i = 0; i < 4; i++)
        #pragma unroll
        for (int j = 0; j < 4; j++) acc[i][j] = (floatx4){0.f, 0.f, 0.f, 0.f};

    for (int c0 = 0; c0 < CC; c0 += 64) {
        #pragma unroll
        for (int p = 0; p < 8; p++)
            __builtin_amdgcn_global_load_lds(
                (const __attribute__((address_space(1))) void*)(srcp[p] + c0),
                (__attribute__((address_space(3))) void*)(Lds + (w * 8 + p) * 512),
                16, 0, 0);
        __syncthreads();
        #pragma unroll
        for (int ks = 0; ks < 2; ks++) {
            int cj = ks * 4 + q;
            half8 af[4], bf[4];
            #pragma unroll
            for (int i = 0; i < 4; i++)
                af[i] = *(const half8*)&Lds[arow[i] + ((cj ^ asw[i]) << 3)];
            #pragma unroll
            for (int j = 0; j < 4; j++)
                bf[j] = *(const half8*)&Lds[brow[j] + ((cj ^ bsw[j]) << 3)];
            #pragma unroll
            for (int i = 0; i < 4; i++)
                #pragma unroll
                for (int j = 0; j < 4; j++)
                    acc[i][j] = __builtin_amdgcn_mfma_f32_16x16x32_f16(af[i], bf[j], acc[i][j], 0, 0, 0);
        }
        __syncthreads();
    }

    // epilogue: fold 4 j-tiles into <=2 class keys, dual-key butterfly, atomicMax
    int wbase = cblk * 128 + wj * 64;     // wave's 64-col window
    int clsLo = wbase / 196;
    #pragma unroll
    for (int i = 0; i < 4; i++) {
        #pragma unroll
        for (int r = 0; r < 4; r++) {
            unsigned long long keyLo = 0ULL, keyHi = 0ULL;
            #pragma unroll
            for (int jt = 0; jt < 4; jt++) {
                float v = acc[i][jt][r];
                int c = wbase + jt * 16 + l15;
                int cls = c / 196;
                int ms = c - cls * 196;
                unsigned int ub = __float_as_uint(v);
                unsigned int su = (ub & 0x80000000u) ? ~ub : (ub | 0x80000000u);
                unsigned long long key = (c < NREAL)
                    ? (((unsigned long long)su << 32) |
                       (unsigned long long)(0xFFFFFFFFu - (unsigned int)ms))
                    : 0ULL;
                if (cls == clsLo) keyLo = (key > keyLo) ? key : keyLo;
                else              keyHi = (key > keyHi) ? key : keyHi;
            }
            #pragma unroll
            for (int sft = 1; sft < 16; sft <<= 1) {
                unsigned long long oL = __shfl_xor(keyLo, sft, 64);
                unsigned long long oH = __shfl_xor(keyHi, sft, 64);
                if (oL > keyLo) keyLo = oL;
                if (oH > keyHi) keyHi = oH;
            }
            if (l15 == 0) {
                int gm = mblk * 128 + wi * 64 + i * 16 + q * 4 + r;
                if (gm < MM) {
                    if (keyLo)
                        atomicMax(&gstat[((size_t)bq * NWAY + clsLo) * MP + gm], keyLo);
                    int clsHi = clsLo + 1;
                    if (keyHi && clsHi < NWAY)
                        atomicMax(&gstat[((size_t)bq * NWAY + clsHi) * MP + gm], keyHi);
                }
            }
        }
    }
}

// ---------------- mutual-NN mask + predict + per-sample CE ----------------
__global__ void k_post(const unsigned long long* __restrict__ gstat,
                       const float* __restrict__ invq,
                       float* __restrict__ sloss, const int* __restrict__ qy) {
    int bq = blockIdx.x;
    int t = threadIdx.x;
    __shared__ float cm[NWAY * MM];
    __shared__ int   ca[NWAY * MM];
    __shared__ float gmax[MM];
    __shared__ int   jst[MM];
    __shared__ int   msk[MM];
    __shared__ float pred[NWAY];

    for (int i = t; i < NWAY * MM; i += 256) {
        int n = i / MM, m = i - n * MM;
        unsigned long long key = gstat[((size_t)bq * NWAY + n) * MP + m];
        unsigned int hi = (unsigned int)(key >> 32);
        unsigned int bits = (hi & 0x80000000u) ? (hi ^ 0x80000000u) : ~hi;
        cm[i] = __uint_as_float(bits) * invq[bq * MM + m];
        ca[i] = (int)(0xFFFFFFFFu - (unsigned int)(key & 0xFFFFFFFFu));
    }
    __syncthreads();

    if (t < MM) {       // cross-class combine: ascending n, strict > == n-major first-index
        float bv = cm[t];
        int bj = ca[t];
        for (int n = 1; n < NWAY; n++) {
            float v = cm[n * MM + t];
            if (v > bv) { bv = v; bj = n * MM + ca[n * MM + t]; }
        }
        gmax[t] = bv; jst[t] = bj;
    }
    __syncthreads();

    if (t < MM) {       // mutual-NN: winner of my support-column group (max gmax, min index)
        int myj = jst[t];
        float myv = gmax[t];
        int lose = 0;
        for (int m2 = 0; m2 < MM; m2++) {
            if (jst[m2] == myj &&
                (gmax[m2] > myv || (gmax[m2] == myv && m2 < t))) lose = 1;
        }
        msk[t] = !lose;
    }
    __syncthreads();

    if (t < NWAY) {
        float p = 0.f;
        for (int m = 0; m < MM; m++) if (msk[m]) p += cm[t * MM + m];
        pred[t] = 2.0f * p;   // TEMPERATURE = 2
    }
    __syncthreads();

    if (t == 0) {
        float pm = pred[0];
        for (int n = 1; n < NWAY; n++) pm = fmaxf(pm, pred[n]);
        float s = 0.f;
        for (int n = 0; n < NWAY; n++) s += expf(pred[n] - pm);
        float lse = pm + logf(s);
        int y = qy[bq];
        sloss[bq] = (lse - pred[y]) * (1.0f / (BB * QQ));
    }
}

// ---------------- final reduce ----------------
__global__ void k_reduce(const float* __restrict__ sloss, float* __restrict__ out) {
    int t = threadIdx.x;
    float s = 0.f;
    for (int i = t; i < BQ; i += 256) s += sloss[i];
    for (int off = 32; off > 0; off >>= 1) s += __shfl_down(s, off, 64);
    __shared__ float part[4];
    if ((t & 63) == 0) part[t >> 6] = s;
    __syncthreads();
    if (t == 0) out[0] = part[0] + part[1] + part[2] + part[3];
}

extern "C" void kernel_launch(void* const* d_in, const int* in_sizes, int n_in,
                              void* d_out, int out_size, void* d_ws, size_t ws_size,
                              hipStream_t stream) {
    const float* sx = (const float*)d_in[0];
    const float* qx = (const float*)d_in[2];
    const int*   qy = (const int*)d_in[3];
    float* out = (float*)d_out;
    float* ws  = (float*)d_ws;

    _Float16* Bpk = (_Float16*)(ws + BPK_OFF);
    _Float16* Apk = (_Float16*)(ws + APK_OFF);
    float* supf = ws + SUPF_OFF;
    unsigned long long* gstat = (unsigned long long*)(ws + GSTAT_OFF);
    float* nrms = ws + NRMS_OFF;
    float* nrmq = ws + NRMQ_OFF;
    float* invs = ws + INVS_OFF;
    float* invq = ws + INVQ_OFF;
    float* sloss = ws + SLOSS_OFF;

    // zero gstat + nrms + nrmq in one shot (contiguous)
    hipMemsetAsync(gstat, 0, (size_t)(2 * GSTAT_N + NRMS_SZ + NRMQ_SZ) * 4, stream);
    hipLaunchKernelGGL(k_mean,   dim3(200),  dim3(256), 0, stream, sx, supf, nrms);
    hipLaunchKernelGGL(k_pack_A, dim3(3000), dim3(256), 0, stream, qx, Apk, nrmq);
    hipLaunchKernelGGL(k_inv,    dim3((NRMS_SZ + NRMQ_SZ + 255) / 256), dim3(256), 0, stream,
                       nrms, invs, NRMS_SZ + NRMQ_SZ);
    hipLaunchKernelGGL(k_packB,  dim3(200),  dim3(256), 0, stream, supf, invs, Bpk);
    hipLaunchKernelGGL(k_sim,    dim3(8 * 38 * 16), dim3(256), 0, stream, Apk, Bpk, gstat);
    hipLaunchKernelGGL(k_post,   dim3(300),  dim3(256), 0, stream, gstat, invq, sloss, qy);
    hipLaunchKernelGGL(k_reduce, dim3(1),    dim3(256), 0, stream, sloss, out);
}

// Round 5
// 449.072 us; speedup vs baseline: 5.2322x; 1.0852x over previous
//
#include <hip/hip_runtime.h>
#include <math.h>

#define NWAY 5
#define KSHOT 5
#define BB 4
#define QQ 75
#define CC 640
#define MM 196
#define BQ (BB*QQ)          // 300
#define MP 208              // packed A rows per bq
#define NCOL 1024           // padded flat col space (980 real)
#define NREAL 980

// ---- ws layout (float offsets) ----
#define BPK_OFF   0
#define BPK_SZF   (BB*NCOL*CC/2)            // 1,310,720 (fp16 region)
#define APK_OFF   (BPK_OFF + BPK_SZF)
#define APK_SZF   ((BQ*MP + 64)*CC/2)       // +64 pad rows so mblk=1 OOB stays in-region
#define GSTAT_OFF (APK_OFF + APK_SZF)       // even -> 8B aligned
#define GSTAT_N   (BQ*NWAY*MP)              // 312,000 u64
#define NRMS_OFF  (GSTAT_OFF + 2*GSTAT_N)
#define NRMS_SZ   (BB*NWAY*MM)              // 3,920
#define NRMQ_OFF  (NRMS_OFF + NRMS_SZ)
#define NRMQ_SZ   (BQ*MM)                   // 58,800

typedef __attribute__((ext_vector_type(8))) _Float16 half8;
typedef __attribute__((ext_vector_type(4))) float floatx4;

// ---------------- fused prep: A-pack (3000 blocks) + B mean-pack (200 blocks) ----------------
__global__ void k_prep(const float* __restrict__ sx, const float* __restrict__ qx,
                       _Float16* __restrict__ Apk, _Float16* __restrict__ Bpk,
                       float* __restrict__ nrmq, float* __restrict__ nrms) {
    __shared__ float T[64 * 197];         // 50,432 B
    int t = threadIdx.x;
    int blk = blockIdx.x;
    if (blk < 3000) {
        // ---- query pack: Apk[bq][m][c] fp16 (unnormalized) + nrmq partials ----
        int bq = blk / 10, cc = blk % 10;
        int c0 = cc * 64;
        const float* Q = qx + (size_t)bq * CC * MM + (size_t)c0 * MM;
        for (int idx = t; idx < 64 * MM; idx += 256) {
            int ci = idx / MM, m = idx - ci * MM;
            T[ci * 197 + m] = Q[idx];
        }
        __syncthreads();
        _Float16* out = Apk + (size_t)bq * MP * CC;
        int mloc = t >> 3, cj8 = t & 7;   // 32 rows x 8 col-groups per pass
        #pragma unroll
        for (int r = 0; r < 7; r++) {
            int mm = r * 32 + mloc;
            if (mm < MP) {
                half8 v;
                #pragma unroll
                for (int k = 0; k < 8; k++) {
                    float f = (mm < MM) ? T[(cj8 * 8 + k) * 197 + mm] : 0.f;
                    v[k] = (_Float16)f;
                }
                *(half8*)&out[(size_t)mm * CC + c0 + cj8 * 8] = v;
            }
        }
        if (t < MM) {
            float ss = 0.f;
            for (int ci = 0; ci < 64; ci++) { float v = T[ci * 197 + t]; ss += v * v; }
            atomicAdd(&nrmq[bq * MM + t], ss);
        }
    } else {
        // ---- support k-shot mean + pack: Bpk[b][col=n*196+ms][c] fp16 (unnormalized) + nrms ----
        int bb = blk - 3000;
        int bn = bb / 10, cc = bb % 10;
        int b = bn / NWAY, n = bn % NWAY;
        int c0 = cc * 64;
        const float* S = sx + (size_t)bn * KSHOT * CC * MM + (size_t)c0 * MM;
        for (int idx = t; idx < 64 * MM; idx += 256) {
            int ci = idx / MM, m = idx - ci * MM;
            float s = 0.f;
            #pragma unroll
            for (int k = 0; k < KSHOT; k++) s += S[(size_t)k * CC * MM + idx];
            T[ci * 197 + m] = s * 0.2f;
        }
        __syncthreads();
        _Float16* out = Bpk + ((size_t)b * NCOL + (size_t)n * MM) * CC;
        int mloc = t >> 3, cj8 = t & 7;
        #pragma unroll
        for (int r = 0; r < 7; r++) {
            int mm = r * 32 + mloc;
            if (mm < MM) {
                half8 v;
                #pragma unroll
                for (int k = 0; k < 8; k++)
                    v[k] = (_Float16)T[(cj8 * 8 + k) * 197 + mm];
                *(half8*)&out[(size_t)mm * CC + c0 + cj8 * 8] = v;
            }
        }
        if (t < MM) {
            float ss = 0.f;
            for (int ci = 0; ci < 64; ci++) { float v = T[ci * 197 + t]; ss += v * v; }
            atomicAdd(&nrms[bn * MM + t], ss);
        }
    }
}

// ---------------- MFMA similarity: 128x128 block, 2x8 wave tiling, segmented epilogue ----------------
// LDS: A 128 rows x 64 halfs (chunks 0-1023), B 128 cols x 64 halfs (chunks 1024-2047).
// Chunk slot j of row m holds global chunk j^(m&7) -> ds_read_b128 2-way aliased (free).
__global__ __launch_bounds__(256, 3) void k_sim(
    const _Float16* __restrict__ Apk, const _Float16* __restrict__ Bpk,
    const float* __restrict__ nrms, unsigned long long* __restrict__ gstat)
{
    __shared__ __align__(16) _Float16 Lds[16384];   // 32,768 B
    int id = blockIdx.x;
    int x = id & 7, s = id >> 3;          // XCD swizzle: 16 blocks of one bq -> same XCD
    int sub = s & 15, bqg = s >> 4;
    int bq = x + (bqg << 3);
    if (bq >= BQ) return;
    int mblk = sub >> 3, cblk = sub & 7;
    int b = bq / QQ;

    int t = threadIdx.x, lane = t & 63, w = t >> 6;
    int q = lane >> 4, l15 = lane & 15;

    const _Float16* Ab = Apk + (size_t)bq * MP * CC + (size_t)(mblk * 128) * CC;
    const _Float16* Bb = Bpk + ((size_t)b * NCOL + (size_t)(cblk * 128)) * CC;
    const _Float16* base = (w < 2) ? Ab : Bb;     // waves 0,1 stage A; 2,3 stage B

    // per-lane 32-bit staging offsets (halfs)
    int voff[8];
    #pragma unroll
    for (int p = 0; p < 8; p++) {
        int chunk = (w * 8 + p) * 64 + lane;
        if (chunk < 1024) {
            int m = chunk >> 3, j = chunk & 7;
            voff[p] = m * CC + ((j ^ (m & 7)) << 3);
        } else {
            int cb = chunk - 1024;
            int jl = cb >> 3, j = cb & 7;
            voff[p] = jl * CC + ((j ^ (jl & 7)) << 3);
        }
    }

    // fragment LDS offsets (halfs): wave w -> rows w*32 + i*16, all 128 cols
    int arow[2], asw[2], brow[8], bsw[8];
    #pragma unroll
    for (int i = 0; i < 2; i++) {
        int m = w * 32 + i * 16 + l15;
        arow[i] = m * 64; asw[i] = m & 7;
    }
    #pragma unroll
    for (int jt = 0; jt < 8; jt++) {
        int jl = jt * 16 + l15;
        brow[jt] = 8192 + jl * 64; bsw[jt] = jl & 7;
    }

    floatx4 acc[2][8];
    #pragma unroll
    for (int i = 0; i < 2; i++)
        #pragma unroll
        for (int j = 0; j < 8; j++) acc[i][j] = (floatx4){0.f, 0.f, 0.f, 0.f};

    for (int c0 = 0; c0 < CC; c0 += 64) {
        #pragma unroll
        for (int p = 0; p < 8; p++)
            __builtin_amdgcn_global_load_lds(
                (const __attribute__((address_space(1))) void*)(base + voff[p] + c0),
                (__attribute__((address_space(3))) void*)(Lds + (w * 8 + p) * 512),
                16, 0, 0);
        __syncthreads();
        #pragma unroll
        for (int ks = 0; ks < 2; ks++) {
            int cj = ks * 4 + q;
            half8 af[2], bf[8];
            #pragma unroll
            for (int i = 0; i < 2; i++)
                af[i] = *(const half8*)&Lds[arow[i] + ((cj ^ asw[i]) << 3)];
            #pragma unroll
            for (int jt = 0; jt < 8; jt++)
                bf[jt] = *(const half8*)&Lds[brow[jt] + ((cj ^ bsw[jt]) << 3)];
            #pragma unroll
            for (int i = 0; i < 2; i++)
                #pragma unroll
                for (int jt = 0; jt < 8; jt++)
                    acc[i][jt] = __builtin_amdgcn_mfma_f32_16x16x32_f16(af[i], bf[jt], acc[i][jt], 0, 0, 0);
        }
        __syncthreads();
    }

    // epilogue: column norm applied here (B packed unnormalized); fold 8 jt into <=2
    // class keys per (i,r), dual-key butterfly, atomicMax
    int wbase = cblk * 128;               // all 4 waves share the col window
    int clsLo = wbase / 196;
    float invv[8]; int ms8[8], isLo[8], valid[8];
    #pragma unroll
    for (int jt = 0; jt < 8; jt++) {
        int c = wbase + jt * 16 + l15;
        int cls = c / 196;
        ms8[jt] = c - cls * 196;
        isLo[jt] = (cls == clsLo);
        valid[jt] = (c < NREAL);
        invv[jt] = valid[jt] ? (1.0f / fmaxf(sqrtf(nrms[b * NREAL + c]), 1e-8f)) : 0.f;
    }
    #pragma unroll
    for (int i = 0; i < 2; i++) {
        #pragma unroll
        for (int r = 0; r < 4; r++) {
            unsigned long long keyLo = 0ULL, keyHi = 0ULL;
            #pragma unroll
            for (int jt = 0; jt < 8; jt++) {
                float v = acc[i][jt][r] * invv[jt];
                unsigned int ub = __float_as_uint(v);
                unsigned int su = (ub & 0x80000000u) ? ~ub : (ub | 0x80000000u);
                unsigned long long key = valid[jt]
                    ? (((unsigned long long)su << 32) |
                       (unsigned long long)(0xFFFFFFFFu - (unsigned int)ms8[jt]))
                    : 0ULL;
                if (isLo[jt]) keyLo = (key > keyLo) ? key : keyLo;
                else          keyHi = (key > keyHi) ? key : keyHi;
            }
            #pragma unroll
            for (int sft = 1; sft < 16; sft <<= 1) {
                unsigned long long oL = __shfl_xor(keyLo, sft, 64);
                unsigned long long oH = __shfl_xor(keyHi, sft, 64);
                if (oL > keyLo) keyLo = oL;
                if (oH > keyHi) keyHi = oH;
            }
            if (l15 == 0) {
                int gm = mblk * 128 + w * 32 + i * 16 + q * 4 + r;
                if (gm < MM) {
                    if (keyLo)
                        atomicMax(&gstat[((size_t)bq * NWAY + clsLo) * MP + gm], keyLo);
                    int clsHi = clsLo + 1;
                    if (keyHi && clsHi < NWAY)
                        atomicMax(&gstat[((size_t)bq * NWAY + clsHi) * MP + gm], keyHi);
                }
            }
        }
    }
}

// ---------------- mutual-NN mask + predict + per-sample CE -> atomicAdd out ----------------
__global__ void k_post(const unsigned long long* __restrict__ gstat,
                       const float* __restrict__ nrmq,
                       float* __restrict__ out, const int* __restrict__ qy) {
    int bq = blockIdx.x;
    int t = threadIdx.x;
    __shared__ float invq_s[MM];
    __shared__ float cm[NWAY * MM];
    __shared__ int   ca[NWAY * MM];
    __shared__ float gmax[MM];
    __shared__ int   jst[MM];
    __shared__ int   msk[MM];
    __shared__ float pred[NWAY];

    if (t < MM) invq_s[t] = 1.0f / fmaxf(sqrtf(nrmq[bq * MM + t]), 1e-8f);
    __syncthreads();

    for (int i = t; i < NWAY * MM; i += 256) {
        int n = i / MM, m = i - n * MM;
        unsigned long long key = gstat[((size_t)bq * NWAY + n) * MP + m];
        unsigned int hi = (unsigned int)(key >> 32);
        unsigned int bits = (hi & 0x80000000u) ? (hi ^ 0x80000000u) : ~hi;
        cm[i] = __uint_as_float(bits) * invq_s[m];
        ca[i] = (int)(0xFFFFFFFFu - (unsigned int)(key & 0xFFFFFFFFu));
    }
    __syncthreads();

    if (t < MM) {       // cross-class combine: ascending n, strict > == n-major first-index
        float bv = cm[t];
        int bj = ca[t];
        for (int n = 1; n < NWAY; n++) {
            float v = cm[n * MM + t];
            if (v > bv) { bv = v; bj = n * MM + ca[n * MM + t]; }
        }
        gmax[t] = bv; jst[t] = bj;
    }
    __syncthreads();

    if (t < MM) {       // mutual-NN: winner of my support-column group (max gmax, min index)
        int myj = jst[t];
        float myv = gmax[t];
        int lose = 0;
        for (int m2 = 0; m2 < MM; m2++) {
            if (jst[m2] == myj &&
                (gmax[m2] > myv || (gmax[m2] == myv && m2 < t))) lose = 1;
        }
        msk[t] = !lose;
    }
    __syncthreads();

    if (t < NWAY) {
        float p = 0.f;
        for (int m = 0; m < MM; m++) if (msk[m]) p += cm[t * MM + m];
        pred[t] = 2.0f * p;   // TEMPERATURE = 2
    }
    __syncthreads();

    if (t == 0) {
        float pm = pred[0];
        for (int n = 1; n < NWAY; n++) pm = fmaxf(pm, pred[n]);
        float s = 0.f;
        for (int n = 0; n < NWAY; n++) s += expf(pred[n] - pm);
        float lse = pm + logf(s);
        int y = qy[bq];
        atomicAdd(out, (lse - pred[y]) * (1.0f / (BB * QQ)));
    }
}

extern "C" void kernel_launch(void* const* d_in, const int* in_sizes, int n_in,
                              void* d_out, int out_size, void* d_ws, size_t ws_size,
                              hipStream_t stream) {
    const float* sx = (const float*)d_in[0];
    const float* qx = (const float*)d_in[2];
    const int*   qy = (const int*)d_in[3];
    float* out = (float*)d_out;
    float* ws  = (float*)d_ws;

    _Float16* Bpk = (_Float16*)(ws + BPK_OFF);
    _Float16* Apk = (_Float16*)(ws + APK_OFF);
    unsigned long long* gstat = (unsigned long long*)(ws + GSTAT_OFF);
    float* nrms = ws + NRMS_OFF;
    float* nrmq = ws + NRMQ_OFF;

    // zero gstat + nrms + nrmq (contiguous) and the output accumulator
    hipMemsetAsync(gstat, 0, (size_t)(2 * GSTAT_N + NRMS_SZ + NRMQ_SZ) * 4, stream);
    hipMemsetAsync(out, 0, 4, stream);
    hipLaunchKernelGGL(k_prep, dim3(3200), dim3(256), 0, stream, sx, qx, Apk, Bpk, nrmq, nrms);
    hipLaunchKernelGGL(k_sim,  dim3(8 * 38 * 16), dim3(256), 0, stream, Apk, Bpk, nrms, gstat);
    hipLaunchKernelGGL(k_post, dim3(300), dim3(256), 0, stream, gstat, nrmq, out, qy);
}